// Round 21
// baseline (128.491 us; speedup 1.0000x reference)
//
#include <hip/hip_runtime.h>
#include <hip/hip_bf16.h>

typedef unsigned short u16;
typedef unsigned int u32;
typedef __attribute__((ext_vector_type(8))) short short8;
typedef __attribute__((ext_vector_type(4))) float f32x4;
typedef __attribute__((ext_vector_type(16))) float f32x16;
typedef __attribute__((ext_vector_type(4))) u32 u32x4;
typedef __attribute__((ext_vector_type(2))) u32 u32x2;

// ---- helpers ----------------------------------------------------------

__device__ __forceinline__ u16 f2b(float f) {
  unsigned u = __float_as_uint(f);
  u = (u + 0x7FFFu + ((u >> 16) & 1u)) >> 16;  // RNE
  return (u16)u;
}

__device__ __forceinline__ u32 pkbf(float lo, float hi) {
  __hip_bfloat162 b = __float22bfloat162_rn(make_float2(lo, hi));  // v_cvt_pk_bf16_f32
  u32 r;
  __builtin_memcpy(&r, &b, 4);
  return r;
}

__device__ __forceinline__ u32x2 plswap(u32 a, u32 b) {
  return __builtin_amdgcn_permlane32_swap(a, b, false, false);
}

__device__ __forceinline__ void gload16(const void* g, void* l) {
  __builtin_amdgcn_global_load_lds(
      (const __attribute__((address_space(1))) void*)g,
      (__attribute__((address_space(3))) void*)l, 16, 0, 0);
}

// ---- fp32 -> bf16: x (4096 blocks) + 4 weights (4x1024 blocks), 1 launch

__global__ __launch_bounds__(256) void cvt_all_kernel(
    const float* __restrict__ x, const float* __restrict__ w0,
    const float* __restrict__ w1, const float* __restrict__ w2,
    const float* __restrict__ w3, u16* __restrict__ xo, u16* __restrict__ o0,
    u16* __restrict__ o1, u16* __restrict__ o2, u16* __restrict__ o3,
    float scale0) {
  const int bid = blockIdx.x;
  const float* in;
  u16* out;
  float scale = 1.f;
  int i;
  if (bid < 4096) {
    in = x; out = xo; i = bid;
  } else {
    const int k = (bid - 4096) >> 10;
    i = (bid - 4096) & 1023;
    in = (k == 0) ? w0 : (k == 1) ? w1 : (k == 2) ? w2 : w3;
    out = (k == 0) ? o0 : (k == 1) ? o1 : (k == 2) ? o2 : o3;
    if (k == 0) scale = scale0;
  }
  int idx = (i * 256 + threadIdx.x) * 4;
  float4 v = *(const float4*)(in + idx);
  unsigned p0 = (unsigned)f2b(v.x * scale) | ((unsigned)f2b(v.y * scale) << 16);
  unsigned p1 = (unsigned)f2b(v.z * scale) | ((unsigned)f2b(v.w * scale) << 16);
  *(uint2*)(out + idx) = make_uint2(p0, p1);
}

// ---- bf16 transpose: V[4096][1024] -> Vt[1024][4096] -------------------

__global__ __launch_bounds__(256) void transpose_kernel(const u16* __restrict__ V,
                                                        u16* __restrict__ Vt) {
  __shared__ u16 t[32][33];
  int bx = blockIdx.x;
  int by = blockIdx.y;
  int c = threadIdx.x & 31, r4 = threadIdx.x >> 5;
#pragma unroll
  for (int i = 0; i < 4; ++i) {
    int row = r4 * 4 + i;
    t[row][c] = V[(size_t)(by * 32 + row) * 1024 + bx * 32 + c];
  }
  __syncthreads();
#pragma unroll
  for (int i = 0; i < 4; ++i) {
    int row = r4 * 4 + i;
    Vt[(size_t)(bx * 32 + row) * 4096 + by * 32 + c] = t[c][row];
  }
}

// ---- GEMM: C[4096][N] tiles = A @ B^T (bf16), BM=128, BK=64 ------------
// Staging: linear LDS dest + inverse-swizzled source + swizzled read
// (verified r14). r21: INCREMENTAL staging pointers (row/sub invariant,
// only k0 varies -> precompute per-lane pointers, += 128B per K-step).

__device__ __forceinline__ void storeC(u16* C, size_t idx, float v) { C[idx] = f2b(v); }
__device__ __forceinline__ void storeC(float* C, size_t idx, float v) { C[idx] = v; }

template <int BN, typename OutT>
__device__ __forceinline__ void gemm_body(const u16* __restrict__ A,
                                          const u16* __restrict__ B,
                                          OutT* __restrict__ C) {
  constexpr int NF = BN / 32;        // B-frags per wave per k-sub
  constexpr int BJ = BN / 32;        // B staging rounds
  __shared__ __align__(16) u16 lA[128 * 64];
  __shared__ __align__(16) u16 lB[BN * 64];
  const int tid = threadIdx.x;
  const int w = tid >> 6, lane = tid & 63, g = lane >> 4, lr = lane & 15;
  const int wr = w >> 1, wc = w & 1;
  const int m0 = blockIdx.y * 128, n0 = blockIdx.x * BN;

  // incremental staging pointers (computed once; advanced per K-step)
  const u16* ap[4];
  const u16* bp[BJ];
#pragma unroll
  for (int j = 0; j < 4; ++j) {
    int c = tid + j * 256;
    int row = c >> 3, sub = (c & 7) ^ (row & 7);
    ap[j] = A + (size_t)(m0 + row) * 1024 + sub * 8;
    if (j < BJ) bp[j] = B + (size_t)(n0 + row) * 1024 + sub * 8;
  }

  f32x4 acc[4][NF] = {};

  for (int k0 = 0; k0 < 1024; k0 += 64) {
#pragma unroll
    for (int j = 0; j < 4; ++j) {
      gload16(ap[j], &lA[(j * 256 + w * 64) * 8]);
      ap[j] += 64;
    }
#pragma unroll
    for (int j = 0; j < BJ; ++j) {
      gload16(bp[j], &lB[(j * 256 + w * 64) * 8]);
      bp[j] += 64;
    }
    __syncthreads();

#pragma unroll
    for (int k2 = 0; k2 < 2; ++k2) {
      short8 af[4], bf[NF];
#pragma unroll
      for (int i = 0; i < 4; ++i) {
        int row = wr * 64 + i * 16 + lr;
        af[i] = *(const short8*)&lA[row * 64 + ((((k2 << 2) | g) ^ (row & 7)) << 3)];
      }
#pragma unroll
      for (int i = 0; i < NF; ++i) {
        int row = wc * (BN / 2) + i * 16 + lr;
        bf[i] = *(const short8*)&lB[row * 64 + ((((k2 << 2) | g) ^ (row & 7)) << 3)];
      }
#pragma unroll
      for (int mi = 0; mi < 4; ++mi)
#pragma unroll
        for (int ni = 0; ni < NF; ++ni)
          acc[mi][ni] = __builtin_amdgcn_mfma_f32_16x16x32_bf16(af[mi], bf[ni],
                                                                acc[mi][ni], 0, 0, 0);
    }
    __syncthreads();
  }

#pragma unroll
  for (int mi = 0; mi < 4; ++mi)
#pragma unroll
    for (int ni = 0; ni < NF; ++ni)
#pragma unroll
      for (int r = 0; r < 4; ++r) {
        size_t row = (size_t)(m0 + wr * 64 + mi * 16 + g * 4 + r);
        size_t col = (size_t)(n0 + wc * (BN / 2) + ni * 16 + lr);
        storeC(C, row * 1024 + col, acc[mi][ni][r]);
      }
}

__global__ __launch_bounds__(256) void gemm_qkv_kernel(
    const u16* __restrict__ A, const u16* __restrict__ W0, const u16* __restrict__ W1,
    const u16* __restrict__ W2, u16* __restrict__ C0, u16* __restrict__ C1,
    u16* __restrict__ C2) {
  int z = blockIdx.z;
  const u16* B = (z == 0) ? W0 : (z == 1) ? W1 : W2;
  u16* C = (z == 0) ? C0 : (z == 1) ? C1 : C2;
  gemm_body<128, u16>(A, B, C);
}

__global__ __launch_bounds__(256) void gemm_out_kernel(const u16* __restrict__ A,
                                                       const u16* __restrict__ B,
                                                       float* __restrict__ C) {
  gemm_body<64, float>(A, B, C);
}

// ---- flash attention: r20 winner + unroll-by-2 static buffers ----------
// block = 512 thr = 8 waves = 2 pairs x 4 q-subtiles; 128 q rows, 1 head.
// Pair p streams 64-key K/V tiles staged via global_load_lds (coalesced,
// XOR-swizzled source + swizzled ds_read), double-buffered, 1 barrier/tile.
// r21: K-loop unrolled by 2 so the buffer index is STATIC -> all 16
// ds_read_b128 per tile become base+immediate-offset (no per-tile address
// VALU; the same mechanism as r20's +18%). Incremental staging pointers,
// unshifted exp2, matrix-pipe row-sum, combine (OA+OB)/(lA+lB).

#define NEGINF (-30000.0f)

__global__ __launch_bounds__(512, 4) void attn_kernel(const u16* __restrict__ Qg,
                                                      const u16* __restrict__ Kg,
                                                      const u16* __restrict__ Vtg,
                                                      u16* __restrict__ Og) {
  // main loop: [pair][buf][K 8KB | V 8KB] = 64KB
  // epilogue reuse: lOf 32KB | pw 16KB | lll 512B
  __shared__ __align__(16) char smem[65536];

  const int tid = threadIdx.x, lane = tid & 63;
  const int w8 = tid >> 6, p = w8 >> 2, qw = w8 & 3;
  const int l31 = lane & 31, hi = lane >> 5;
  const int bid = blockIdx.x;
  const int h = bid & 15;                    // head (head->XCD pinned)
  const int i32 = bid >> 4;                  // 0..31
  const int qb = (i32 < 16) ? (31 - i32) : (i32 - 16);  // co-resident pairs sum 31
  const int qs = qb * 128;                   // block's first q row
  const int qsw = qs + qw * 32;              // wave's first q row
  const int iters = qb + 1;                  // tiles per pair (64-key tiles)
  const int kstart = p ? iters : 0;
  const int dtw = qsw >> 6;                  // wave's diagonal 64-key tile
  const int swz = (l31 & 7) << 4;

  const u32x4 onesu = {0x3F803F80u, 0x3F803F80u, 0x3F803F80u, 0x3F803F80u};
  const short8 ones = __builtin_bit_cast(short8, onesu);  // bf16 1.0 x8

  // Q fragment (A-operand rows = queries)
  short8 qf[4];
  {
    const u16* Qp = Qg + (size_t)(qsw + l31) * 1024 + h * 64 + hi * 8;
#pragma unroll
    for (int kc = 0; kc < 4; ++kc) qf[kc] = *(const short8*)(Qp + kc * 16);
  }

  // incremental staging pointers (computed once; advanced per tile)
  const int j0 = qw * 2;
  const u16* kp[2];
  const u16* vp[2];
#pragma unroll
  for (int jj = 0; jj < 2; ++jj) {
    const int row = ((j0 + jj) << 3) + (lane >> 3);
    const int c = (lane & 7) ^ (row & 7);  // inverse-swizzled source chunk
    kp[jj] = Kg + (size_t)(kstart * 64 + row) * 1024 + h * 64 + c * 8;
    vp[jj] = Vtg + (size_t)(h * 64 + row) * 4096 + kstart * 64 + c * 8;
  }

  auto stage = [&](int b) {
    char* Kb = smem + (((p << 1) | b) << 14);
    char* Vb = Kb + 8192;
#pragma unroll
    for (int jj = 0; jj < 2; ++jj) {
      gload16(kp[jj], Kb + ((j0 + jj) << 10));
      gload16(vp[jj], Vb + ((j0 + jj) << 10));
      kp[jj] += 64 * 1024;  // next 64-key K tile
      vp[jj] += 64;         // next 64-key Vt tile
    }
  };

  f32x16 ot[2] = {};
  f32x16 lacc = {};

  // one K/V tile: prefetch (optional) + compute + barrier. buf is a
  // call-site literal -> ds_read addresses fold to base+imm offsets.
  auto tile = [&](int kt, int buf, bool prefetch) {
    if (prefetch) stage(buf ^ 1);

    const bool doCompute = (p == 0) || (kt <= dtw);
    if (doCompute) {
      const char* Kb = smem + (((p << 1) | buf) << 14);
      const char* Vb = Kb + 8192;

      // S^T = K . Q^T for two 32-key subtiles
      f32x16 st0 = {}, st1 = {};
#pragma unroll
      for (int kc = 0; kc < 4; ++kc) {
        short8 k0 = *(const short8*)(Kb + l31 * 128 + ((((kc << 1) | hi) << 4) ^ swz));
        st0 = __builtin_amdgcn_mfma_f32_32x32x16_bf16(k0, qf[kc], st0, 0, 0, 0);
      }
#pragma unroll
      for (int kc = 0; kc < 4; ++kc) {
        short8 k1 =
            *(const short8*)(Kb + 4096 + l31 * 128 + ((((kc << 1) | hi) << 4) ^ swz));
        st1 = __builtin_amdgcn_mfma_f32_32x32x16_bf16(k1, qf[kc], st1, 0, 0, 0);
      }

      if (kt == dtw) {  // causal mask on the diagonal tile (either pair)
        const int q = qsw + l31;
#pragma unroll
        for (int r = 0; r < 16; ++r) {
          int key = kt * 64 + (r & 3) + 8 * (r >> 2) + 4 * hi;
          if (key > q) st0[r] = NEGINF;
          if (key + 32 > q) st1[r] = NEGINF;
        }
      }

      // unshifted exp (scale-invariant softmax; bounded scores, f32-safe)
#pragma unroll
      for (int r = 0; r < 16; ++r) {
        st0[r] = __builtin_amdgcn_exp2f(st0[r]);
        st1[r] = __builtin_amdgcn_exp2f(st1[r]);
      }

      // per-subtile: pack P -> bf16 B-frags; row-sum via mfma(ones, pa);
      // then PV MFMAs
#pragma unroll
      for (int kt2 = 0; kt2 < 2; ++kt2) {
        const f32x16& st = kt2 ? st1 : st0;
        short8 pa[2];
#pragma unroll
        for (int ks = 0; ks < 2; ++ks) {
          const int b = 8 * ks;
          u32 pk0 = pkbf(st[b + 0], st[b + 1]);
          u32 pk1 = pkbf(st[b + 2], st[b + 3]);
          u32 pk2 = pkbf(st[b + 4], st[b + 5]);
          u32 pk3 = pkbf(st[b + 6], st[b + 7]);
          u32x2 r02 = plswap(pk0, pk2);
          u32x2 r13 = plswap(pk1, pk3);
          u32x4 t;
          t.x = r02.x;
          t.y = r13.x;
          t.z = r02.y;
          t.w = r13.y;
          pa[ks] = __builtin_bit_cast(short8, t);
        }
        lacc = __builtin_amdgcn_mfma_f32_32x32x16_bf16(ones, pa[0], lacc, 0, 0, 0);
        lacc = __builtin_amdgcn_mfma_f32_32x32x16_bf16(ones, pa[1], lacc, 0, 0, 0);
#pragma unroll
        for (int dt = 0; dt < 2; ++dt)
#pragma unroll
          for (int ks = 0; ks < 2; ++ks) {
            short8 vfv = *(const short8*)(Vb + dt * 4096 + l31 * 128 +
                                          (((kt2 * 4 + ks * 2 + hi) << 4) ^ swz));
            ot[dt] =
                __builtin_amdgcn_mfma_f32_32x32x16_bf16(vfv, pa[ks], ot[dt], 0, 0, 0);
          }
      }
    }
    __syncthreads();
  };

  stage(0);
  __syncthreads();

  int it = 0;
  for (; it + 2 <= iters; it += 2) {
    tile(kstart + it, 0, true);                    // even tile, buf 0
    tile(kstart + it + 1, 1, it + 2 < iters);      // odd tile,  buf 1
  }
  if (it < iters) tile(kstart + it, 0, false);     // trailing even tile

  // ---- combine of the two KV-halves: (O_A + O_B) / (l_A + l_B) ----------
  __syncthreads();  // done with staging buffers; repurpose smem
  float* lOfw = (float*)smem + (qw << 11);              // 8KB per subtile
  char* pw = smem + 32768 + (qw << 12);                 // 4KB per subtile
  float* lll = (float*)(smem + 49152) + (qw << 5);      // 128B per subtile
  if (p == 0) {
#pragma unroll
    for (int dt = 0; dt < 2; ++dt)
#pragma unroll
      for (int r = 0; r < 16; ++r) {
        int d = dt * 32 + (r & 3) + 8 * (r >> 2) + 4 * hi;
        lOfw[d * 32 + l31] = ot[dt][r];
      }
    if (hi == 0) lll[l31] = lacc[0];
  }
  __syncthreads();
  if (p == 1) {
    float inv = 1.0f / (lll[l31] + lacc[0]);
#pragma unroll
    for (int dt = 0; dt < 2; ++dt)
#pragma unroll
      for (int r = 0; r < 16; ++r) {
        int d = dt * 32 + (r & 3) + 8 * (r >> 2) + 4 * hi;
        float val = (lOfw[d * 32 + l31] + ot[dt][r]) * inv;
        *(u16*)(pw + l31 * 128 + ((d * 2) ^ ((l31 & 7) << 4))) = f2b(val);
      }
  }
  __syncthreads();
  if (p == 1) {
    const int row = lane >> 1;
#pragma unroll
    for (int ii = 0; ii < 4; ++ii) {
      int c = (lane & 1) * 4 + ii;
      short8 v = *(const short8*)(pw + row * 128 + ((c * 16) ^ ((row & 7) << 4)));
      *(short8*)(Og + (size_t)(qsw + row) * 1024 + h * 64 + c * 8) = v;
    }
  }
}

// ---- launcher ----------------------------------------------------------

extern "C" void kernel_launch(void* const* d_in, const int* in_sizes, int n_in,
                              void* d_out, int out_size, void* d_ws, size_t ws_size,
                              hipStream_t stream) {
  const float* x = (const float*)d_in[0];
  const float* Wq = (const float*)d_in[1];
  const float* Wk = (const float*)d_in[2];
  const float* Wv = (const float*)d_in[3];
  const float* Wo = (const float*)d_in[4];
  float* out = (float*)d_out;
  char* ws = (char*)d_ws;
  const size_t MB = 1024 * 1024;

  u16* xb  = (u16*)(ws);
  u16* wqb = (u16*)(ws + 8 * MB);
  u16* wkb = (u16*)(ws + 10 * MB);
  u16* wvb = (u16*)(ws + 12 * MB);
  u16* wob = (u16*)(ws + 14 * MB);
  u16* Qb  = (u16*)(ws + 16 * MB);
  u16* Kb  = (u16*)(ws + 24 * MB);
  u16* Vb  = (u16*)(ws + 32 * MB);
  u16* Vtb = (u16*)(ws + 40 * MB);
  u16* att = xb;

  // 0.125 = 1/sqrt(D); *log2(e) so softmax runs in exp2 domain
  const float qscale = 0.125f * 1.4426950408889634f;

  cvt_all_kernel<<<8192, 256, 0, stream>>>(x, Wq, Wk, Wv, Wo, xb, wqb, wkb, wvb,
                                           wob, qscale);

  gemm_qkv_kernel<<<dim3(8, 32, 3), 256, 0, stream>>>(xb, wqb, wkb, wvb, Qb, Kb,
                                                      Vb);
  transpose_kernel<<<dim3(32, 128), 256, 0, stream>>>(Vb, Vtb);
  attn_kernel<<<512, 512, 0, stream>>>(Qb, Kb, Vtb, att);
  gemm_out_kernel<<<dim3(16, 32), 256, 0, stream>>>(att, wob, out);
}

// Round 22
// 118.928 us; speedup vs baseline: 1.0804x; 1.0804x over previous
//
#include <hip/hip_runtime.h>
#include <hip/hip_bf16.h>

typedef unsigned short u16;
typedef unsigned int u32;
typedef __attribute__((ext_vector_type(8))) short short8;
typedef __attribute__((ext_vector_type(4))) float f32x4;
typedef __attribute__((ext_vector_type(16))) float f32x16;
typedef __attribute__((ext_vector_type(4))) u32 u32x4;
typedef __attribute__((ext_vector_type(2))) u32 u32x2;

// ---- helpers ----------------------------------------------------------

__device__ __forceinline__ u16 f2b(float f) {
  unsigned u = __float_as_uint(f);
  u = (u + 0x7FFFu + ((u >> 16) & 1u)) >> 16;  // RNE
  return (u16)u;
}

__device__ __forceinline__ u32 pkbf(float lo, float hi) {
  __hip_bfloat162 b = __float22bfloat162_rn(make_float2(lo, hi));  // v_cvt_pk_bf16_f32
  u32 r;
  __builtin_memcpy(&r, &b, 4);
  return r;
}

__device__ __forceinline__ u32x2 plswap(u32 a, u32 b) {
  return __builtin_amdgcn_permlane32_swap(a, b, false, false);
}

__device__ __forceinline__ void gload16(const void* g, void* l) {
  __builtin_amdgcn_global_load_lds(
      (const __attribute__((address_space(1))) void*)g,
      (__attribute__((address_space(3))) void*)l, 16, 0, 0);
}

// ---- fp32 -> bf16: x (4096 blocks) + 4 weights (4x1024 blocks), 1 launch

__global__ __launch_bounds__(256) void cvt_all_kernel(
    const float* __restrict__ x, const float* __restrict__ w0,
    const float* __restrict__ w1, const float* __restrict__ w2,
    const float* __restrict__ w3, u16* __restrict__ xo, u16* __restrict__ o0,
    u16* __restrict__ o1, u16* __restrict__ o2, u16* __restrict__ o3,
    float scale0) {
  const int bid = blockIdx.x;
  const float* in;
  u16* out;
  float scale = 1.f;
  int i;
  if (bid < 4096) {
    in = x; out = xo; i = bid;
  } else {
    const int k = (bid - 4096) >> 10;
    i = (bid - 4096) & 1023;
    in = (k == 0) ? w0 : (k == 1) ? w1 : (k == 2) ? w2 : w3;
    out = (k == 0) ? o0 : (k == 1) ? o1 : (k == 2) ? o2 : o3;
    if (k == 0) scale = scale0;
  }
  int idx = (i * 256 + threadIdx.x) * 4;
  float4 v = *(const float4*)(in + idx);
  unsigned p0 = (unsigned)f2b(v.x * scale) | ((unsigned)f2b(v.y * scale) << 16);
  unsigned p1 = (unsigned)f2b(v.z * scale) | ((unsigned)f2b(v.w * scale) << 16);
  *(uint2*)(out + idx) = make_uint2(p0, p1);
}

// ---- bf16 transpose: V[4096][1024] -> Vt[1024][4096] -------------------

__global__ __launch_bounds__(256) void transpose_kernel(const u16* __restrict__ V,
                                                        u16* __restrict__ Vt) {
  __shared__ u16 t[32][33];
  int bx = blockIdx.x;
  int by = blockIdx.y;
  int c = threadIdx.x & 31, r4 = threadIdx.x >> 5;
#pragma unroll
  for (int i = 0; i < 4; ++i) {
    int row = r4 * 4 + i;
    t[row][c] = V[(size_t)(by * 32 + row) * 1024 + bx * 32 + c];
  }
  __syncthreads();
#pragma unroll
  for (int i = 0; i < 4; ++i) {
    int row = r4 * 4 + i;
    Vt[(size_t)(bx * 32 + row) * 4096 + by * 32 + c] = t[c][row];
  }
}

// ---- GEMM: C[4096][N] tiles = A @ B^T (bf16), BM=128, BK=64 ------------
// r20/r14 form: staging addresses recomputed per K-step (r21's incremental
// pointer arrays = 16 live VGPRs -> occupancy cliff, +9.5us. Reverted.)

__device__ __forceinline__ void storeC(u16* C, size_t idx, float v) { C[idx] = f2b(v); }
__device__ __forceinline__ void storeC(float* C, size_t idx, float v) { C[idx] = v; }

template <int BN, typename OutT>
__device__ __forceinline__ void gemm_body(const u16* __restrict__ A,
                                          const u16* __restrict__ B,
                                          OutT* __restrict__ C) {
  constexpr int NF = BN / 32;        // B-frags per wave per k-sub
  constexpr int BJ = BN / 32;        // B staging rounds
  __shared__ __align__(16) u16 lA[128 * 64];
  __shared__ __align__(16) u16 lB[BN * 64];
  const int tid = threadIdx.x;
  const int w = tid >> 6, lane = tid & 63, g = lane >> 4, lr = lane & 15;
  const int wr = w >> 1, wc = w & 1;
  const int m0 = blockIdx.y * 128, n0 = blockIdx.x * BN;

  f32x4 acc[4][NF] = {};

  for (int k0 = 0; k0 < 1024; k0 += 64) {
#pragma unroll
    for (int j = 0; j < 4; ++j) {
      int c = tid + j * 256;
      int row = c >> 3, sub = (c & 7) ^ (row & 7);
      gload16(A + (size_t)(m0 + row) * 1024 + k0 + sub * 8,
              &lA[(j * 256 + w * 64) * 8]);
      if (j < BJ)
        gload16(B + (size_t)(n0 + row) * 1024 + k0 + sub * 8,
                &lB[(j * 256 + w * 64) * 8]);
    }
    __syncthreads();

#pragma unroll
    for (int k2 = 0; k2 < 2; ++k2) {
      short8 af[4], bf[NF];
#pragma unroll
      for (int i = 0; i < 4; ++i) {
        int row = wr * 64 + i * 16 + lr;
        af[i] = *(const short8*)&lA[row * 64 + ((((k2 << 2) | g) ^ (row & 7)) << 3)];
      }
#pragma unroll
      for (int i = 0; i < NF; ++i) {
        int row = wc * (BN / 2) + i * 16 + lr;
        bf[i] = *(const short8*)&lB[row * 64 + ((((k2 << 2) | g) ^ (row & 7)) << 3)];
      }
#pragma unroll
      for (int mi = 0; mi < 4; ++mi)
#pragma unroll
        for (int ni = 0; ni < NF; ++ni)
          acc[mi][ni] = __builtin_amdgcn_mfma_f32_16x16x32_bf16(af[mi], bf[ni],
                                                                acc[mi][ni], 0, 0, 0);
    }
    __syncthreads();
  }

#pragma unroll
  for (int mi = 0; mi < 4; ++mi)
#pragma unroll
    for (int ni = 0; ni < NF; ++ni)
#pragma unroll
      for (int r = 0; r < 4; ++r) {
        size_t row = (size_t)(m0 + wr * 64 + mi * 16 + g * 4 + r);
        size_t col = (size_t)(n0 + wc * (BN / 2) + ni * 16 + lr);
        storeC(C, row * 1024 + col, acc[mi][ni][r]);
      }
}

__global__ __launch_bounds__(256) void gemm_qkv_kernel(
    const u16* __restrict__ A, const u16* __restrict__ W0, const u16* __restrict__ W1,
    const u16* __restrict__ W2, u16* __restrict__ C0, u16* __restrict__ C1,
    u16* __restrict__ C2) {
  int z = blockIdx.z;
  const u16* B = (z == 0) ? W0 : (z == 1) ? W1 : W2;
  u16* C = (z == 0) ? C0 : (z == 1) ? C1 : C2;
  gemm_body<128, u16>(A, B, C);
}

__global__ __launch_bounds__(256) void gemm_out_kernel(const u16* __restrict__ A,
                                                       const u16* __restrict__ B,
                                                       float* __restrict__ C) {
  gemm_body<64, float>(A, B, C);
}

// ---- flash attention: r21 verified (unroll-by-2 static buffers) --------
// block = 512 thr = 8 waves = 2 pairs x 4 q-subtiles; 128 q rows, 1 head.
// Pair p streams 64-key K/V tiles staged via global_load_lds (coalesced,
// XOR-swizzled source + swizzled ds_read), double-buffered, 1 barrier/tile.
// K-loop unrolled by 2 (static buffer index -> ds_read base+imm offsets);
// incremental staging pointers (2 ptrs, fits reg budget); unshifted exp2;
// matrix-pipe row-sum; combine (OA+OB)/(lA+lB).

#define NEGINF (-30000.0f)

__global__ __launch_bounds__(512, 4) void attn_kernel(const u16* __restrict__ Qg,
                                                      const u16* __restrict__ Kg,
                                                      const u16* __restrict__ Vtg,
                                                      u16* __restrict__ Og) {
  // main loop: [pair][buf][K 8KB | V 8KB] = 64KB
  // epilogue reuse: lOf 32KB | pw 16KB | lll 512B
  __shared__ __align__(16) char smem[65536];

  const int tid = threadIdx.x, lane = tid & 63;
  const int w8 = tid >> 6, p = w8 >> 2, qw = w8 & 3;
  const int l31 = lane & 31, hi = lane >> 5;
  const int bid = blockIdx.x;
  const int h = bid & 15;                    // head (head->XCD pinned)
  const int i32 = bid >> 4;                  // 0..31
  const int qb = (i32 < 16) ? (31 - i32) : (i32 - 16);  // co-resident pairs sum 31
  const int qs = qb * 128;                   // block's first q row
  const int qsw = qs + qw * 32;              // wave's first q row
  const int iters = qb + 1;                  // tiles per pair (64-key tiles)
  const int kstart = p ? iters : 0;
  const int dtw = qsw >> 6;                  // wave's diagonal 64-key tile
  const int swz = (l31 & 7) << 4;

  const u32x4 onesu = {0x3F803F80u, 0x3F803F80u, 0x3F803F80u, 0x3F803F80u};
  const short8 ones = __builtin_bit_cast(short8, onesu);  // bf16 1.0 x8

  // Q fragment (A-operand rows = queries)
  short8 qf[4];
  {
    const u16* Qp = Qg + (size_t)(qsw + l31) * 1024 + h * 64 + hi * 8;
#pragma unroll
    for (int kc = 0; kc < 4; ++kc) qf[kc] = *(const short8*)(Qp + kc * 16);
  }

  // incremental staging pointers (computed once; advanced per tile)
  const int j0 = qw * 2;
  const u16* kp[2];
  const u16* vp[2];
#pragma unroll
  for (int jj = 0; jj < 2; ++jj) {
    const int row = ((j0 + jj) << 3) + (lane >> 3);
    const int c = (lane & 7) ^ (row & 7);  // inverse-swizzled source chunk
    kp[jj] = Kg + (size_t)(kstart * 64 + row) * 1024 + h * 64 + c * 8;
    vp[jj] = Vtg + (size_t)(h * 64 + row) * 4096 + kstart * 64 + c * 8;
  }

  auto stage = [&](int b) {
    char* Kb = smem + (((p << 1) | b) << 14);
    char* Vb = Kb + 8192;
#pragma unroll
    for (int jj = 0; jj < 2; ++jj) {
      gload16(kp[jj], Kb + ((j0 + jj) << 10));
      gload16(vp[jj], Vb + ((j0 + jj) << 10));
      kp[jj] += 64 * 1024;  // next 64-key K tile
      vp[jj] += 64;         // next 64-key Vt tile
    }
  };

  f32x16 ot[2] = {};
  f32x16 lacc = {};

  // one K/V tile: prefetch (optional) + compute + barrier. buf is a
  // call-site literal -> ds_read addresses fold to base+imm offsets.
  auto tile = [&](int kt, int buf, bool prefetch) {
    if (prefetch) stage(buf ^ 1);

    const bool doCompute = (p == 0) || (kt <= dtw);
    if (doCompute) {
      const char* Kb = smem + (((p << 1) | buf) << 14);
      const char* Vb = Kb + 8192;

      // S^T = K . Q^T for two 32-key subtiles
      f32x16 st0 = {}, st1 = {};
#pragma unroll
      for (int kc = 0; kc < 4; ++kc) {
        short8 k0 = *(const short8*)(Kb + l31 * 128 + ((((kc << 1) | hi) << 4) ^ swz));
        st0 = __builtin_amdgcn_mfma_f32_32x32x16_bf16(k0, qf[kc], st0, 0, 0, 0);
      }
#pragma unroll
      for (int kc = 0; kc < 4; ++kc) {
        short8 k1 =
            *(const short8*)(Kb + 4096 + l31 * 128 + ((((kc << 1) | hi) << 4) ^ swz));
        st1 = __builtin_amdgcn_mfma_f32_32x32x16_bf16(k1, qf[kc], st1, 0, 0, 0);
      }

      if (kt == dtw) {  // causal mask on the diagonal tile (either pair)
        const int q = qsw + l31;
#pragma unroll
        for (int r = 0; r < 16; ++r) {
          int key = kt * 64 + (r & 3) + 8 * (r >> 2) + 4 * hi;
          if (key > q) st0[r] = NEGINF;
          if (key + 32 > q) st1[r] = NEGINF;
        }
      }

      // unshifted exp (scale-invariant softmax; bounded scores, f32-safe)
#pragma unroll
      for (int r = 0; r < 16; ++r) {
        st0[r] = __builtin_amdgcn_exp2f(st0[r]);
        st1[r] = __builtin_amdgcn_exp2f(st1[r]);
      }

      // per-subtile: pack P -> bf16 B-frags; row-sum via mfma(ones, pa);
      // then PV MFMAs
#pragma unroll
      for (int kt2 = 0; kt2 < 2; ++kt2) {
        const f32x16& st = kt2 ? st1 : st0;
        short8 pa[2];
#pragma unroll
        for (int ks = 0; ks < 2; ++ks) {
          const int b = 8 * ks;
          u32 pk0 = pkbf(st[b + 0], st[b + 1]);
          u32 pk1 = pkbf(st[b + 2], st[b + 3]);
          u32 pk2 = pkbf(st[b + 4], st[b + 5]);
          u32 pk3 = pkbf(st[b + 6], st[b + 7]);
          u32x2 r02 = plswap(pk0, pk2);
          u32x2 r13 = plswap(pk1, pk3);
          u32x4 t;
          t.x = r02.x;
          t.y = r13.x;
          t.z = r02.y;
          t.w = r13.y;
          pa[ks] = __builtin_bit_cast(short8, t);
        }
        lacc = __builtin_amdgcn_mfma_f32_32x32x16_bf16(ones, pa[0], lacc, 0, 0, 0);
        lacc = __builtin_amdgcn_mfma_f32_32x32x16_bf16(ones, pa[1], lacc, 0, 0, 0);
#pragma unroll
        for (int dt = 0; dt < 2; ++dt)
#pragma unroll
          for (int ks = 0; ks < 2; ++ks) {
            short8 vfv = *(const short8*)(Vb + dt * 4096 + l31 * 128 +
                                          (((kt2 * 4 + ks * 2 + hi) << 4) ^ swz));
            ot[dt] =
                __builtin_amdgcn_mfma_f32_32x32x16_bf16(vfv, pa[ks], ot[dt], 0, 0, 0);
          }
      }
    }
    __syncthreads();
  };

  stage(0);
  __syncthreads();

  int it = 0;
  for (; it + 2 <= iters; it += 2) {
    tile(kstart + it, 0, true);                    // even tile, buf 0
    tile(kstart + it + 1, 1, it + 2 < iters);      // odd tile,  buf 1
  }
  if (it < iters) tile(kstart + it, 0, false);     // trailing even tile

  // ---- combine of the two KV-halves: (O_A + O_B) / (l_A + l_B) ----------
  __syncthreads();  // done with staging buffers; repurpose smem
  float* lOfw = (float*)smem + (qw << 11);              // 8KB per subtile
  char* pw = smem + 32768 + (qw << 12);                 // 4KB per subtile
  float* lll = (float*)(smem + 49152) + (qw << 5);      // 128B per subtile
  if (p == 0) {
#pragma unroll
    for (int dt = 0; dt < 2; ++dt)
#pragma unroll
      for (int r = 0; r < 16; ++r) {
        int d = dt * 32 + (r & 3) + 8 * (r >> 2) + 4 * hi;
        lOfw[d * 32 + l31] = ot[dt][r];
      }
    if (hi == 0) lll[l31] = lacc[0];
  }
  __syncthreads();
  if (p == 1) {
    float inv = 1.0f / (lll[l31] + lacc[0]);
#pragma unroll
    for (int dt = 0; dt < 2; ++dt)
#pragma unroll
      for (int r = 0; r < 16; ++r) {
        int d = dt * 32 + (r & 3) + 8 * (r >> 2) + 4 * hi;
        float val = (lOfw[d * 32 + l31] + ot[dt][r]) * inv;
        *(u16*)(pw + l31 * 128 + ((d * 2) ^ ((l31 & 7) << 4))) = f2b(val);
      }
  }
  __syncthreads();
  if (p == 1) {
    const int row = lane >> 1;
#pragma unroll
    for (int ii = 0; ii < 4; ++ii) {
      int c = (lane & 1) * 4 + ii;
      short8 v = *(const short8*)(pw + row * 128 + ((c * 16) ^ ((row & 7) << 4)));
      *(short8*)(Og + (size_t)(qsw + row) * 1024 + h * 64 + c * 8) = v;
    }
  }
}

// ---- launcher ----------------------------------------------------------

extern "C" void kernel_launch(void* const* d_in, const int* in_sizes, int n_in,
                              void* d_out, int out_size, void* d_ws, size_t ws_size,
                              hipStream_t stream) {
  const float* x = (const float*)d_in[0];
  const float* Wq = (const float*)d_in[1];
  const float* Wk = (const float*)d_in[2];
  const float* Wv = (const float*)d_in[3];
  const float* Wo = (const float*)d_in[4];
  float* out = (float*)d_out;
  char* ws = (char*)d_ws;
  const size_t MB = 1024 * 1024;

  u16* xb  = (u16*)(ws);
  u16* wqb = (u16*)(ws + 8 * MB);
  u16* wkb = (u16*)(ws + 10 * MB);
  u16* wvb = (u16*)(ws + 12 * MB);
  u16* wob = (u16*)(ws + 14 * MB);
  u16* Qb  = (u16*)(ws + 16 * MB);
  u16* Kb  = (u16*)(ws + 24 * MB);
  u16* Vb  = (u16*)(ws + 32 * MB);
  u16* Vtb = (u16*)(ws + 40 * MB);
  u16* att = xb;

  // 0.125 = 1/sqrt(D); *log2(e) so softmax runs in exp2 domain
  const float qscale = 0.125f * 1.4426950408889634f;

  cvt_all_kernel<<<8192, 256, 0, stream>>>(x, Wq, Wk, Wv, Wo, xb, wqb, wkb, wvb,
                                           wob, qscale);

  gemm_qkv_kernel<<<dim3(8, 32, 3), 256, 0, stream>>>(xb, wqb, wkb, wvb, Qb, Kb,
                                                      Vb);
  transpose_kernel<<<dim3(32, 128), 256, 0, stream>>>(Vb, Vtb);
  attn_kernel<<<512, 512, 0, stream>>>(Qb, Kb, Vtb, att);
  gemm_out_kernel<<<dim3(16, 32), 256, 0, stream>>>(att, wob, out);
}